// Round 11
// baseline (183.931 us; speedup 1.0000x reference)
//
#include <hip/hip_runtime.h>
#include <stdint.h>
#include <math.h>

// ===== Problem constants =====
#define BB 8
#define LL 4096
#define HH 4
#define DD 8      // IN_DIM
#define VV 4      // FFN_V
#define DEPTH 8   // FFN_DEPTH
#define NBIT 8
#define NROW 131072   // B*L*H
#define CHUNK 64
#define NCHUNK 64     // L / CHUNK
#define GRID 1024
#define NLEAF 32      // barrier tree leaves (32 blocks/leaf, separate cachelines)

typedef int v4i __attribute__((ext_vector_type(4)));

__device__ __forceinline__ uint32_t rotl32(uint32_t v, int r){ return (v<<r)|(v>>(32-r)); }

__device__ __forceinline__ void tf2x32(uint32_t k0, uint32_t k1, uint32_t x0, uint32_t x1,
                                       uint32_t& o0, uint32_t& o1){
  uint32_t ks2 = k0 ^ k1 ^ 0x1BD11BDAu;
  x0 += k0; x1 += k1;
  x0+=x1; x1=rotl32(x1,13); x1^=x0;
  x0+=x1; x1=rotl32(x1,15); x1^=x0;
  x0+=x1; x1=rotl32(x1,26); x1^=x0;
  x0+=x1; x1=rotl32(x1, 6); x1^=x0;
  x0+=k1; x1+=ks2+1u;
  x0+=x1; x1=rotl32(x1,17); x1^=x0;
  x0+=x1; x1=rotl32(x1,29); x1^=x0;
  x0+=x1; x1=rotl32(x1,16); x1^=x0;
  x0+=x1; x1=rotl32(x1,24); x1^=x0;
  x0+=ks2; x1+=k0+2u;
  x0+=x1; x1=rotl32(x1,13); x1^=x0;
  x0+=x1; x1=rotl32(x1,15); x1^=x0;
  x0+=x1; x1=rotl32(x1,26); x1^=x0;
  x0+=x1; x1=rotl32(x1, 6); x1^=x0;
  x0+=k0; x1+=k1+3u;
  x0+=x1; x1=rotl32(x1,17); x1^=x0;
  x0+=x1; x1=rotl32(x1,29); x1^=x0;
  x0+=x1; x1=rotl32(x1,16); x1^=x0;
  x0+=x1; x1=rotl32(x1,24); x1^=x0;
  x0+=k1; x1+=ks2+4u;
  x0+=x1; x1=rotl32(x1,13); x1^=x0;
  x0+=x1; x1=rotl32(x1,15); x1^=x0;
  x0+=x1; x1=rotl32(x1,26); x1^=x0;
  x0+=x1; x1=rotl32(x1, 6); x1^=x0;
  x0+=ks2; x1+=k0+5u;
  o0 = x0; o1 = x1;
}

struct K2 { uint32_t a, b; };
__device__ __forceinline__ K2 kfold(K2 k, uint32_t d){
  K2 r; tf2x32(k.a, k.b, 0u, d, r.a, r.b); return r;
}

// partitionable threefry (jax >= 0.4.36 default): bits = o0 ^ o1 of tf(key, [0, p])
__device__ __forceinline__ uint32_t rbits(K2 k, uint32_t p){
  uint32_t o0, o1; tf2x32(k.a, k.b, 0u, p, o0, o1); return o0 ^ o1;
}

__device__ __forceinline__ float bits2u(uint32_t b){
  return __uint_as_float((b >> 9) | 0x3f800000u) - 1.0f;
}

// ===== Bit-exact XLA-CPU style math (Cephes/Eigen structure, strict f32, no FMA) =====
__device__ __forceinline__ float xla_expf(float x){
  #pragma clang fp contract(off)
  const float exp_hi = 88.3762626647950f;
  const float exp_lo = -88.3762626647949f;
  const float log2e  = 1.44269504088896341f;
  const float c1 = 0.693359375f;
  const float c2 = -2.12194440e-4f;
  float xc = fmaxf(fminf(x, exp_hi), exp_lo);
  float fx = floorf(xc * log2e + 0.5f);
  float tmp = fx * c1;
  float z1  = fx * c2;
  float r = xc - tmp;
  r = r - z1;
  float z = r * r;
  float y = 1.9875691500E-4f;
  y = y * r + 1.3981999507E-3f;
  y = y * r + 8.3334519073E-3f;
  y = y * r + 4.1665795894E-2f;
  y = y * r + 1.6666665459E-1f;
  y = y * r + 5.0000001201E-1f;
  y = y * z + r;
  y = y + 1.0f;
  int emm0 = (int)fx + 127;
  float scale = __int_as_float(emm0 << 23);
  return fmaxf(y * scale, x);
}

__device__ __forceinline__ float xla_logf(float a){
  #pragma clang fp contract(off)
  float x = fmaxf(a, __uint_as_float(0x00800000u));
  uint32_t bits = __float_as_uint(x);
  int em = (int)(bits >> 23) - 126;
  x = __uint_as_float((bits & 0x007fffffu) | 0x3f000000u);
  float e = (float)em;
  bool mlt = x < 0.707106781186547524f;
  float tmp1 = mlt ? x : 0.0f;
  float xm = x - 1.0f;
  e = e - (mlt ? 1.0f : 0.0f);
  xm = xm + tmp1;
  float z = xm * xm;
  float y = 7.0376836292E-2f;
  y = y * xm + (-1.1514610310E-1f);
  y = y * xm + 1.1676998740E-1f;
  y = y * xm + (-1.2420140846E-1f);
  y = y * xm + 1.4249322787E-1f;
  y = y * xm + (-1.6668057665E-1f);
  y = y * xm + 2.0000714765E-1f;
  y = y * xm + (-2.4999993993E-1f);
  y = y * xm + 3.3333331174E-1f;
  y = y * xm;
  y = y * z;
  y = e * (-2.12194440e-4f) + y;
  y = y - 0.5f * z;
  float res = xm + y;
  res = e * 0.693359375f + res;
  return res;
}

__device__ __forceinline__ float xla_log1pf(float x){
  #pragma clang fp contract(off)
  if (fabsf(x) < 1e-4f){
    return ((-0.5f * x) + 1.0f) * x;
  }
  return xla_logf(1.0f + x);
}

__device__ __forceinline__ float xla_logaddexp(float a, float b){
  #pragma clang fp contract(off)
  float m = fmaxf(a, b);
  float d = a - b;
  return m + xla_log1pf(xla_expf(-fabsf(d)));
}

template<int NV>
__device__ __forceinline__ float neg_lse_neg(const float* v){
  #pragma clang fp contract(off)
  float m = -v[0];
  #pragma unroll
  for (int i = 1; i < NV; i++) m = fmaxf(m, -v[i]);
  float s = 0.f;
  #pragma unroll
  for (int i = 0; i < NV; i++) s = s + xla_expf((-v[i]) - m);
  return -(xla_logf(s) + m);
}

// sigmoid exactly as XLA LogisticExpander: 1/(1+exp(-w))
__device__ __forceinline__ float xla_sigmoid(float w){
  #pragma clang fp contract(off)
  float e = xla_expf(-w);
  return 1.0f / (1.0f + e);
}

// fast soft-AND for analog-only paths: -logaddexp(-a,-b). andf(x, 1e30f)==x.
__device__ __forceinline__ float andf(float a, float b){
  float na = -a, nb = -b;
  float m = fmaxf(na, nb);
  float d = fabsf(na - nb);
  return -(m + log1pf(expf(-d)));
}
#define AND_IDENT 1e30f

// ===== coherence-point access helpers (sc0 sc1 = system scope) =====
__device__ __forceinline__ void cstore_u8(uint8_t* p, uint32_t v){
  asm volatile("global_store_byte %0, %1, off sc0 sc1" :: "v"(p), "v"(v) : "memory");
}
__device__ __forceinline__ void cstore_f32(float* p, float v){
  asm volatile("global_store_dword %0, %1, off sc0 sc1" :: "v"(p), "v"(v) : "memory");
}
__device__ __forceinline__ uint32_t cload_u8(const uint8_t* p){
  uint32_t v;
  asm volatile("global_load_ubyte %0, %1, off sc0 sc1\n\ts_waitcnt vmcnt(0)"
               : "=v"(v) : "v"(p) : "memory");
  return v;
}
__device__ __forceinline__ float cload_f32(const float* p){
  float v;
  asm volatile("global_load_dword %0, %1, off sc0 sc1\n\ts_waitcnt vmcnt(0)"
               : "=v"(v) : "v"(p) : "memory");
  return v;
}
__device__ __forceinline__ uint32_t cload_u32(const uint32_t* p){
  uint32_t v;
  asm volatile("global_load_dword %0, %1, off sc0 sc1\n\ts_waitcnt vmcnt(0)"
               : "=v"(v) : "v"(p) : "memory");
  return v;
}
__device__ __forceinline__ v4i cload_b128(const v4i* p){
  v4i v;
  asm volatile("global_load_dwordx4 %0, %1, off sc0 sc1\n\ts_waitcnt vmcnt(0)"
               : "=v"(v) : "v"(p) : "memory");
  return v;
}

// ===== fence-free tree barrier (round-10 verified) =====
__device__ __forceinline__ void gbar(uint32_t* leaves, uint32_t* root, uint32_t epoch){
  __syncthreads();                    // all waves drain stores (waitcnt before s_barrier)
  if (threadIdx.x == 0){
    uint32_t leaf = blockIdx.x & (NLEAF - 1);
    uint32_t old = atomicAdd(&leaves[leaf * 32], 1u);    // 128B-spaced lines
    if (old + 1u == epoch * (GRID / NLEAF))              // last of this epoch at leaf
      atomicAdd(root, 1u);
    int slp = 1;
    while (cload_u32(root) < epoch * NLEAF){
      for (int i = 0; i < slp; i++) __builtin_amdgcn_s_sleep(15);  // 960 cy
      if (slp < 4) slp <<= 1;
    }
  }
  __syncthreads();
}

// ===== k_pre (82 blocks): sigFK/sigFV + flag + s0 + keys + barrier zero =====
__global__ __launch_bounds__(256) void k_pre(const uint32_t* xw, int* flag,
                      const float* s0w, int* s0code, float* s0s,
                      const float* fk, const float* fv,
                      float* sigFK, float* sigFV, uint32_t* keys, uint32_t* barmem){
  int i = blockIdx.x * 256 + threadIdx.x;
  if (i < 16320) sigFK[i] = xla_sigmoid(fk[i]);
  else if (i < 16320 + 4096) sigFV[i - 16320] = xla_sigmoid(fv[i - 16320]);

  if (blockIdx.x == 1){
    for (int k = threadIdx.x; k < 1025; k += 256) barmem[k] = 0u;
  }
  if (blockIdx.x == 0){
    __shared__ int any;
    int t = threadIdx.x;
    if (t == 0) any = 0;
    __syncthreads();
    int bad = 0;
    for (int k = t; k < 1024; k += 256){
      uint32_t w = xw[k];
      if (w != 0u && w != 1u && w != 0x3F800000u) bad = 1;
    }
    if (bad) atomicOr(&any, 1);
    __syncthreads();
    if (t == 0) *flag = any;          // 1 -> u8 layout, 0 -> 4-byte layout

    if (t < 32){
      int b = t >> 2, h = t & 3;
      K2 root{0u, 42u};
      K2 sk = kfold(root, 3u);
      float v[NBIT];
      uint32_t code = 0;
      #pragma unroll
      for (int j = 0; j < NBIT; j++){
        float w = s0w[h*NBIT + j];
        uint32_t p = (uint32_t)((b*4 + h)*NBIT + j);
        float u = bits2u(rbits(sk, p));
        bool bit = u < xla_sigmoid(w);
        code |= (bit ? 1u : 0u) << (NBIT - 1 - j);
        v[j] = bit ? w : -w;
      }
      s0code[t] = (int)code;
      s0s[t]    = neg_lse_neg<NBIT>(v);
    }
    if (t == 0){
      K2 root{0u, 42u};
      K2 rngT = kfold(root, 1u);
      for (int d = 0; d < DEPTH; d++){
        K2 kd = kfold(rngT, (uint32_t)d);
        keys[2*d] = kd.a; keys[2*d+1] = kd.b;
        K2 lk = kfold(rngT, 100u + (uint32_t)d);
        keys[16+2*d] = lk.a; keys[16+2*d+1] = lk.b;
      }
      K2 vk = kfold(rngT, 999u);
      keys[32] = vk.a; keys[33] = vk.b;
      K2 tk = kfold(root, 2u);
      keys[34] = tk.a; keys[35] = tk.b;
    }
  }
}

// ===== Fused phases 1-4; 1024 blocks co-resident (4/CU via launch bounds) =====
__global__ __launch_bounds__(256, 4) void k_fused(
    const void* xraw, const float* xs, const float* fv,
    const float* table, float* out,
    uint8_t* xcode, float* xss, uint8_t* tcode, float* tabs,
    uint8_t* F, uint8_t* zOut, float* P, float* T,
    const int* s0code, const float* s0s, const int* flag,
    const float* sigFK, const float* sigFV, const uint32_t* keys,
    uint32_t* leaves, uint32_t* rootc){

  __shared__ v4i sT4[256];         // 4 KB tcode tile (phases 2/3)
  __shared__ v4i sF4[1024];        // 16 KB F tile (phase 3)
  __shared__ uint8_t sXC[CHUNK];
  __shared__ float carryL[4];
  uint8_t* sT = (uint8_t*)sT4;
  uint8_t* sF = (uint8_t*)sF4;
  const int blk = blockIdx.x;
  const int t = threadIdx.x;

  // ---------- Phase 1: pair-split FFN (all blocks; 2 lanes per row) ----------
  // Even lane handles j=0..3, odd lane j=4..7 of row r = global_thread/2.
  // lor exchanged via shuffles (exact bit moves); lse8/routing/support computed
  // redundantly on BOTH lanes (identical inputs -> identical bits; within-wave
  // lockstep makes asymmetric idle cost the same cycles anyway).
  {
    int g = blk * 256 + t;
    int lane = t & 63;
    bool isA = (t & 1) == 0;
    int r = g >> 1;                  // row 0..131071
    int n = r >> 2;
    int h = r & 3;
    int jb = isA ? 0 : 4;            // my j-range: jb..jb+3
    bool u8mode = (*flag != 0);
    const uint8_t* x8   = (const uint8_t*)xraw;
    const uint32_t* x32 = (const uint32_t*)xraw;

    // L-table for my 4 j's (identical op sequence to reference per (d,j))
    float L0[4], L1[4], L2[4], L3[4];
    #pragma unroll
    for (int jj = 0; jj < 4; jj++){
      int j = jb + jj;
      bool qb = u8mode ? (x8[n*DD + j] != 0) : (x32[n*DD + j] != 0u);
      float v = xs[n*DD + j];
      float q = qb ? v : -v;
      float A0 = -xla_logaddexp(-0.0f, q);
      float A1 = -xla_logaddexp(-1.0f, q);
      float B0 = -xla_logaddexp(-0.0f, -q);
      float B1 = -xla_logaddexp(-1.0f, -q);
      L0[jj] = xla_logaddexp(A0, B0);
      L1[jj] = xla_logaddexp(A1, B0);
      L2[jj] = xla_logaddexp(A0, B1);
      L3[jj] = xla_logaddexp(A1, B1);
    }

    const float* hbase = sigFK + (size_t)h * 255 * 16;
    float cur[8];                    // my half of the current node's sigmoids
    *(float4*)(cur)     = *(const float4*)(hbase + jb*2);
    *(float4*)(cur + 4) = *(const float4*)(hbase + jb*2 + 4);

    uint32_t ix = 0;
    float support = 0.f;

    for (int d = 0; d < 7; d++){
      float cl[8], cr[8];            // my halves of both children
      {
        const float* cb = hbase + (size_t)((2 << d) - 1 + 2*(int)ix) * 16 + jb*2;
        *(float4*)(cl)     = *(const float4*)(cb);
        *(float4*)(cl + 4) = *(const float4*)(cb + 4);
        *(float4*)(cr)     = *(const float4*)(cb + 16);
        *(float4*)(cr + 4) = *(const float4*)(cb + 20);
      }
      K2 kd{keys[2*d], keys[2*d+1]};
      float myl[4];
      #pragma unroll
      for (int jj = 0; jj < 4; jj++){
        int j = jb + jj;
        uint32_t p1 = (uint32_t)r * 16u + 2u*(uint32_t)j;
        float u1 = bits2u(rbits(kd, p1));
        float u2 = bits2u(rbits(kd, p1 + 1u));
        bool b1 = u1 < cur[2*jj];
        bool b2 = u2 < cur[2*jj + 1];
        float t01 = b1 ? L1[jj] : L0[jj];
        float t23 = b1 ? L3[jj] : L2[jj];
        myl[jj] = b2 ? t23 : t01;
      }
      float lor[8];
      #pragma unroll
      for (int i = 0; i < 4; i++){
        lor[i]     = __shfl(myl[i], lane & 62, 64);   // even lane's values (j 0..3)
        lor[4 + i] = __shfl(myl[i], lane | 1, 64);    // odd lane's values (j 4..7)
      }
      float lor_s = neg_lse_neg<DD>(lor);
      K2 lk{keys[16+2*d], keys[16+2*d+1]};
      float ul = bits2u(rbits(lk, (uint32_t)r));
      bool lb = ul < xla_sigmoid(lor_s);
      float ls = lb ? lor_s : -lor_s;
      ix = 2u*ix + (lb ? 1u : 0u);
      support = (d == 0) ? ls : -xla_logaddexp(-support, -ls);
      #pragma unroll
      for (int q = 0; q < 8; q++) cur[q] = lb ? cr[q] : cl[q];
    }

    // depth 7 (peeled): prefetch both leaf value rows (8 contiguous floats each)
    float fvv[8], sfv[8];
    {
      const float* fb = fv    + (size_t)(h*256 + 2*(int)ix) * VV;
      const float* sb = sigFV + (size_t)(h*256 + 2*(int)ix) * VV;
      *(float4*)(fvv)     = *(const float4*)(fb);
      *(float4*)(fvv + 4) = *(const float4*)(fb + 4);
      *(float4*)(sfv)     = *(const float4*)(sb);
      *(float4*)(sfv + 4) = *(const float4*)(sb + 4);
    }
    {
      const int d = 7;
      K2 kd{keys[2*d], keys[2*d+1]};
      float myl[4];
      #pragma unroll
      for (int jj = 0; jj < 4; jj++){
        int j = jb + jj;
        uint32_t p1 = (uint32_t)r * 16u + 2u*(uint32_t)j;
        float u1 = bits2u(rbits(kd, p1));
        float u2 = bits2u(rbits(kd, p1 + 1u));
        bool b1 = u1 < cur[2*jj];
        bool b2 = u2 < cur[2*jj + 1];
        float t01 = b1 ? L1[jj] : L0[jj];
        float t23 = b1 ? L3[jj] : L2[jj];
        myl[jj] = b2 ? t23 : t01;
      }
      float lor[8];
      #pragma unroll
      for (int i = 0; i < 4; i++){
        lor[i]     = __shfl(myl[i], lane & 62, 64);
        lor[4 + i] = __shfl(myl[i], lane | 1, 64);
      }
      float lor_s = neg_lse_neg<DD>(lor);
      K2 lk{keys[16+2*d], keys[16+2*d+1]};
      float ul = bits2u(rbits(lk, (uint32_t)r));
      bool lb = ul < xla_sigmoid(lor_s);
      float ls = lb ? lor_s : -lor_s;
      support = -xla_logaddexp(-support, -ls);
      #pragma unroll
      for (int c = 0; c < VV; c++){
        fvv[c] = lb ? fvv[4+c] : fvv[c];
        sfv[c] = lb ? sfv[4+c] : sfv[c];
      }
    }

    K2 vk{keys[32], keys[33]};
    float vs[VV];
    uint32_t code = 0;
    #pragma unroll
    for (int c = 0; c < VV; c++){
      float u = bits2u(rbits(vk, (uint32_t)r*4u + (uint32_t)c));
      bool b = u < sfv[c];
      code |= (b ? 1u : 0u) << (VV - 1 - c);
      float sv = b ? fvv[c] : -fvv[c];
      vs[c] = -xla_logaddexp(-sv, -support);
    }
    if (isA){
      cstore_u8(xcode + r, code);
      cstore_f32(xss + r, neg_lse_neg<VV>(vs));
    }

    // ---- table item on odd lanes: idx = r, exact 1:1 coverage ----
    if (!isA){
      int idx = r;
      int rem = idx & 16383;
      K2 tk{keys[34], keys[35]};
      float4 w0 = *(const float4*)(table + (size_t)rem*NBIT);
      float4 w1 = *(const float4*)(table + (size_t)rem*NBIT + 4);
      float w[NBIT] = {w0.x,w0.y,w0.z,w0.w,w1.x,w1.y,w1.z,w1.w};
      float v[NBIT];
      uint32_t tc = 0;
      #pragma unroll
      for (int j = 0; j < NBIT; j++){
        float u = bits2u(rbits(tk, (uint32_t)idx * 8u + (uint32_t)j));
        bool bit = u < xla_sigmoid(w[j]);
        tc |= (bit ? 1u : 0u) << (NBIT - 1 - j);
        v[j] = bit ? w[j] : -w[j];
      }
      cstore_u8(tcode + idx, tc);
      cstore_f32(tabs + idx, neg_lse_neg<NBIT>(v));
    }
  }
  gbar(leaves, rootc, 1u);

  // ---------- Phase 2: per-chunk all-state maps F (2 vblocks per block) ----------
  for (int v = blk; v < 2048; v += 1024){
    int c  = v & 63;
    int bh = v >> 6;
    int b = bh >> 2, h = bh & 3;
    const int rowbase = (b*64 + h*16) * 256;
    sT4[t] = cload_b128((const v4i*)(tcode + rowbase) + t);
    if (t < CHUNK){
      sXC[t] = (uint8_t)cload_u8(xcode + (b*LL + c*CHUNK + t)*HH + h);
    }
    __syncthreads();
    int cur = t;
    #pragma unroll 8
    for (int k = 0; k < CHUNK; k++){
      cur = sT[(int)sXC[k]*256 + cur];
    }
    cstore_u8(F + (size_t)v*256 + t, (uint32_t)cur);
    __syncthreads();
  }
  gbar(leaves, rootc, 2u);

  // ---------- Phase 3: replay chunk + score scan (4 waves/block, LDS F tile) ----------
  if (blk < 512){
    int bh = blk >> 4;
    int b = bh >> 2, h = bh & 3;
    int w = t >> 6, lane = t & 63;
    int c = (blk & 15)*4 + w;
    const int rowbase = (b*64 + h*16) * 256;
    sT4[t] = cload_b128((const v4i*)(tcode + rowbase) + t);
    const v4i* Fb4 = (const v4i*)(F + (size_t)bh * 16384);
    #pragma unroll
    for (int i = 0; i < 4; i++) sF4[t + 256*i] = cload_b128(Fb4 + t + 256*i);

    int l = c*CHUNK + lane;
    int r = (b*LL + l)*HH + h;
    int   xcv = (int)cload_u8(xcode + r);
    float xsv = cload_f32(xss + r);
    __syncthreads();

    int z = s0code[bh];
    for (int k = 0; k < c; k++) z = sF[k*256 + z];

    int aReg = 0, zReg = 0;
    for (int k = 0; k < CHUNK; k++){
      int xck = __shfl(xcv, k, 64);
      int a = xck*256 + z;
      z = sT[a];
      if (lane == k){ aReg = a; zReg = z; }
    }

    float p = andf(cload_f32(tabs + rowbase + aReg), xsv);
    #pragma unroll
    for (int off = 1; off < 64; off <<= 1){
      float o = __shfl_up(p, off, 64);
      if (lane >= off) p = andf(o, p);
    }
    int vblk = bh*64 + c;
    cstore_u8(zOut + vblk*CHUNK + lane, (uint32_t)zReg);
    cstore_f32(P + vblk*CHUNK + lane, p);
    if (lane == 63) cstore_f32(T + vblk, p);
  }
  gbar(leaves, rootc, 3u);

  // ---------- Phase 4: score carry + coalesced emit (blocks 0..511) ----------
  if (blk < 512){
    int c = blk & 63;
    int b = blk >> 6;
    int w = t >> 6, lane = t & 63;

    float val = (lane < c) ? cload_f32(T + (b*4 + w)*64 + lane) : AND_IDENT;
    #pragma unroll
    for (int off = 1; off < 64; off <<= 1){
      float o = __shfl_xor(val, off, 64);
      val = andf(val, o);
    }
    float carry = andf(val, s0s[b*4 + w]);
    if (lane == 0) carryL[w] = carry;
    __syncthreads();

    int k = t >> 2, h = t & 3;
    int cblk = (b*4 + h)*64 + c;
    int z = (int)cload_u8(zOut + cblk*CHUNK + k);
    float sc = andf(carryL[h], cload_f32(P + cblk*CHUNK + k));

    size_t base = (size_t)blk*2048 + (size_t)t*8;
    float4 b0, b1;
    b0.x = (float)((z >> 7) & 1); b0.y = (float)((z >> 6) & 1);
    b0.z = (float)((z >> 5) & 1); b0.w = (float)((z >> 4) & 1);
    b1.x = (float)((z >> 3) & 1); b1.y = (float)((z >> 2) & 1);
    b1.z = (float)((z >> 1) & 1); b1.w = (float)( z       & 1);
    float4 s4; s4.x = sc; s4.y = sc; s4.z = sc; s4.w = sc;
    *(float4*)(out + base)     = b0;
    *(float4*)(out + base + 4) = b1;
    *(float4*)(out + 1048576 + base)     = s4;
    *(float4*)(out + 1048576 + base + 4) = s4;
  }
}

extern "C" void kernel_launch(void* const* d_in, const int* in_sizes, int n_in,
                              void* d_out, int out_size, void* d_ws, size_t ws_size,
                              hipStream_t stream) {
  const void*  x      = d_in[0];
  const float* xs     = (const float*)d_in[1];
  const float* fk     = (const float*)d_in[2];
  const float* fv     = (const float*)d_in[3];
  const float* table  = (const float*)d_in[4];
  const float* s0w    = (const float*)d_in[5];
  float* out          = (float*)d_out;

  uint8_t* ws = (uint8_t*)d_ws;
  uint8_t* xcode_ = ws;                              // 131072 B
  uint8_t* tcode_ = ws + 131072;                     // 131072 B
  uint8_t* F_     = ws + 262144;                     // 524288 B
  float*   xss_   = (float*)(ws + 786432);           // 524288 B
  float*   tabs_  = (float*)(ws + 1310720);          // 524288 B
  uint8_t* zOut_  = ws + 1835008;                    // 131072 B
  float*   P_     = (float*)(ws + 1966080);          // 524288 B
  float*   T_     = (float*)(ws + 2490368);          // 8192 B
  int*     s0code_= (int*)  (ws + 2498560);          // 128 B
  float*   s0s_   = (float*)(ws + 2498688);          // 128 B
  int*     flag_  = (int*)  (ws + 2498816);          // 4 B
  float*   sigFK_ = (float*)(ws + 2499072);          // 65280 B
  float*   sigFV_ = (float*)(ws + 2564352);          // 16384 B
  uint32_t* keys_ = (uint32_t*)(ws + 2580736);       // 144 B
  uint32_t* barmem_=(uint32_t*)(ws + 2581504);       // 4100 B: 1024 leaf words + root
  uint32_t* leaves_= barmem_;                        // leaf i at leaves_[i*32] (128B apart)
  uint32_t* rootc_ = barmem_ + 1024;

  k_pre  <<<82, 256, 0, stream>>>((const uint32_t*)x, flag_, s0w, s0code_, s0s_,
                                  fk, fv, sigFK_, sigFV_, keys_, barmem_);
  k_fused<<<GRID, 256, 0, stream>>>(x, xs, fv, table, out,
                                    xcode_, xss_, tcode_, tabs_,
                                    F_, zOut_, P_, T_,
                                    s0code_, s0s_, flag_, sigFK_, sigFV_, keys_,
                                    leaves_, rootc_);
}

// Round 12
// 167.884 us; speedup vs baseline: 1.0956x; 1.0956x over previous
//
#include <hip/hip_runtime.h>
#include <stdint.h>
#include <math.h>

// ===== Problem constants =====
#define BB 8
#define LL 4096
#define HH 4
#define DD 8      // IN_DIM
#define VV 4      // FFN_V
#define DEPTH 8   // FFN_DEPTH
#define NBIT 8
#define NROW 131072   // B*L*H
#define CHUNK 64
#define NCHUNK 64     // L / CHUNK
#define GRID 1024
#define NLEAF 32      // barrier tree leaves (32 blocks/leaf, separate cachelines)

typedef int v4i __attribute__((ext_vector_type(4)));

__device__ __forceinline__ uint32_t rotl32(uint32_t v, int r){ return (v<<r)|(v>>(32-r)); }

__device__ __forceinline__ void tf2x32(uint32_t k0, uint32_t k1, uint32_t x0, uint32_t x1,
                                       uint32_t& o0, uint32_t& o1){
  uint32_t ks2 = k0 ^ k1 ^ 0x1BD11BDAu;
  x0 += k0; x1 += k1;
  x0+=x1; x1=rotl32(x1,13); x1^=x0;
  x0+=x1; x1=rotl32(x1,15); x1^=x0;
  x0+=x1; x1=rotl32(x1,26); x1^=x0;
  x0+=x1; x1=rotl32(x1, 6); x1^=x0;
  x0+=k1; x1+=ks2+1u;
  x0+=x1; x1=rotl32(x1,17); x1^=x0;
  x0+=x1; x1=rotl32(x1,29); x1^=x0;
  x0+=x1; x1=rotl32(x1,16); x1^=x0;
  x0+=x1; x1=rotl32(x1,24); x1^=x0;
  x0+=ks2; x1+=k0+2u;
  x0+=x1; x1=rotl32(x1,13); x1^=x0;
  x0+=x1; x1=rotl32(x1,15); x1^=x0;
  x0+=x1; x1=rotl32(x1,26); x1^=x0;
  x0+=x1; x1=rotl32(x1, 6); x1^=x0;
  x0+=k0; x1+=k1+3u;
  x0+=x1; x1=rotl32(x1,17); x1^=x0;
  x0+=x1; x1=rotl32(x1,29); x1^=x0;
  x0+=x1; x1=rotl32(x1,16); x1^=x0;
  x0+=x1; x1=rotl32(x1,24); x1^=x0;
  x0+=k1; x1+=ks2+4u;
  x0+=x1; x1=rotl32(x1,13); x1^=x0;
  x0+=x1; x1=rotl32(x1,15); x1^=x0;
  x0+=x1; x1=rotl32(x1,26); x1^=x0;
  x0+=x1; x1=rotl32(x1, 6); x1^=x0;
  x0+=ks2; x1+=k0+5u;
  o0 = x0; o1 = x1;
}

struct K2 { uint32_t a, b; };
__device__ __forceinline__ K2 kfold(K2 k, uint32_t d){
  K2 r; tf2x32(k.a, k.b, 0u, d, r.a, r.b); return r;
}

// partitionable threefry (jax >= 0.4.36 default): bits = o0 ^ o1 of tf(key, [0, p])
__device__ __forceinline__ uint32_t rbits(K2 k, uint32_t p){
  uint32_t o0, o1; tf2x32(k.a, k.b, 0u, p, o0, o1); return o0 ^ o1;
}

__device__ __forceinline__ float bits2u(uint32_t b){
  return __uint_as_float((b >> 9) | 0x3f800000u) - 1.0f;
}

// ===== Bit-exact XLA-CPU style math (Cephes/Eigen structure, strict f32, no FMA) =====
__device__ __forceinline__ float xla_expf(float x){
  #pragma clang fp contract(off)
  const float exp_hi = 88.3762626647950f;
  const float exp_lo = -88.3762626647949f;
  const float log2e  = 1.44269504088896341f;
  const float c1 = 0.693359375f;
  const float c2 = -2.12194440e-4f;
  float xc = fmaxf(fminf(x, exp_hi), exp_lo);
  float fx = floorf(xc * log2e + 0.5f);
  float tmp = fx * c1;
  float z1  = fx * c2;
  float r = xc - tmp;
  r = r - z1;
  float z = r * r;
  float y = 1.9875691500E-4f;
  y = y * r + 1.3981999507E-3f;
  y = y * r + 8.3334519073E-3f;
  y = y * r + 4.1665795894E-2f;
  y = y * r + 1.6666665459E-1f;
  y = y * r + 5.0000001201E-1f;
  y = y * z + r;
  y = y + 1.0f;
  int emm0 = (int)fx + 127;
  float scale = __int_as_float(emm0 << 23);
  return fmaxf(y * scale, x);
}

__device__ __forceinline__ float xla_logf(float a){
  #pragma clang fp contract(off)
  float x = fmaxf(a, __uint_as_float(0x00800000u));
  uint32_t bits = __float_as_uint(x);
  int em = (int)(bits >> 23) - 126;
  x = __uint_as_float((bits & 0x007fffffu) | 0x3f000000u);
  float e = (float)em;
  bool mlt = x < 0.707106781186547524f;
  float tmp1 = mlt ? x : 0.0f;
  float xm = x - 1.0f;
  e = e - (mlt ? 1.0f : 0.0f);
  xm = xm + tmp1;
  float z = xm * xm;
  float y = 7.0376836292E-2f;
  y = y * xm + (-1.1514610310E-1f);
  y = y * xm + 1.1676998740E-1f;
  y = y * xm + (-1.2420140846E-1f);
  y = y * xm + 1.4249322787E-1f;
  y = y * xm + (-1.6668057665E-1f);
  y = y * xm + 2.0000714765E-1f;
  y = y * xm + (-2.4999993993E-1f);
  y = y * xm + 3.3333331174E-1f;
  y = y * xm;
  y = y * z;
  y = e * (-2.12194440e-4f) + y;
  y = y - 0.5f * z;
  float res = xm + y;
  res = e * 0.693359375f + res;
  return res;
}

__device__ __forceinline__ float xla_log1pf(float x){
  #pragma clang fp contract(off)
  if (fabsf(x) < 1e-4f){
    return ((-0.5f * x) + 1.0f) * x;
  }
  return xla_logf(1.0f + x);
}

__device__ __forceinline__ float xla_logaddexp(float a, float b){
  #pragma clang fp contract(off)
  float m = fmaxf(a, b);
  float d = a - b;
  return m + xla_log1pf(xla_expf(-fabsf(d)));
}

template<int NV>
__device__ __forceinline__ float neg_lse_neg(const float* v){
  #pragma clang fp contract(off)
  float m = -v[0];
  #pragma unroll
  for (int i = 1; i < NV; i++) m = fmaxf(m, -v[i]);
  float s = 0.f;
  #pragma unroll
  for (int i = 0; i < NV; i++) s = s + xla_expf((-v[i]) - m);
  return -(xla_logf(s) + m);
}

// sigmoid exactly as XLA LogisticExpander: 1/(1+exp(-w))
__device__ __forceinline__ float xla_sigmoid(float w){
  #pragma clang fp contract(off)
  float e = xla_expf(-w);
  return 1.0f / (1.0f + e);
}

// fast soft-AND for analog-only paths: -logaddexp(-a,-b). andf(x, 1e30f)==x.
__device__ __forceinline__ float andf(float a, float b){
  float na = -a, nb = -b;
  float m = fmaxf(na, nb);
  float d = fabsf(na - nb);
  return -(m + log1pf(expf(-d)));
}
#define AND_IDENT 1e30f

// ===== coherence-point access helpers (sc0 sc1 = system scope) =====
// Stores write through to the coherence point; loads bypass stale L1/XCD-L2.
// This removes ALL buffer_wbl2/buffer_inv cache-maintenance from the barrier
// (round-9 residual: ~39us/barrier = 2048 full-L2 flush/inv ops serialized
// per XCD). Data visibility: sc1 store -> wave vmcnt drain (at __syncthreads)
// -> arrival atomic -> consumer sc1 load.
__device__ __forceinline__ void cstore_u8(uint8_t* p, uint32_t v){
  asm volatile("global_store_byte %0, %1, off sc0 sc1" :: "v"(p), "v"(v) : "memory");
}
__device__ __forceinline__ void cstore_f32(float* p, float v){
  asm volatile("global_store_dword %0, %1, off sc0 sc1" :: "v"(p), "v"(v) : "memory");
}
__device__ __forceinline__ uint32_t cload_u8(const uint8_t* p){
  uint32_t v;
  asm volatile("global_load_ubyte %0, %1, off sc0 sc1\n\ts_waitcnt vmcnt(0)"
               : "=v"(v) : "v"(p) : "memory");
  return v;
}
__device__ __forceinline__ float cload_f32(const float* p){
  float v;
  asm volatile("global_load_dword %0, %1, off sc0 sc1\n\ts_waitcnt vmcnt(0)"
               : "=v"(v) : "v"(p) : "memory");
  return v;
}
__device__ __forceinline__ uint32_t cload_u32(const uint32_t* p){
  uint32_t v;
  asm volatile("global_load_dword %0, %1, off sc0 sc1\n\ts_waitcnt vmcnt(0)"
               : "=v"(v) : "v"(p) : "memory");
  return v;
}
__device__ __forceinline__ v4i cload_b128(const v4i* p){
  v4i v;
  asm volatile("global_load_dwordx4 %0, %1, off sc0 sc1\n\ts_waitcnt vmcnt(0)"
               : "=v"(v) : "v"(p) : "memory");
  return v;
}

// ===== fence-free tree barrier (round-10 verified) =====
__device__ __forceinline__ void gbar(uint32_t* leaves, uint32_t* root, uint32_t epoch){
  __syncthreads();                    // all waves drain stores (waitcnt before s_barrier)
  if (threadIdx.x == 0){
    uint32_t leaf = blockIdx.x & (NLEAF - 1);
    uint32_t old = atomicAdd(&leaves[leaf * 32], 1u);    // 128B-spaced lines
    if (old + 1u == epoch * (GRID / NLEAF))              // last of this epoch at leaf
      atomicAdd(root, 1u);
    int slp = 1;
    while (cload_u32(root) < epoch * NLEAF){
      for (int i = 0; i < slp; i++) __builtin_amdgcn_s_sleep(15);  // 960 cy
      if (slp < 4) slp <<= 1;
    }
  }
  __syncthreads();
}

// ===== k_pre (82 blocks): sigFK/sigFV + flag + s0 + keys + barrier zero =====
__global__ __launch_bounds__(256) void k_pre(const uint32_t* xw, int* flag,
                      const float* s0w, int* s0code, float* s0s,
                      const float* fk, const float* fv,
                      float* sigFK, float* sigFV, uint32_t* keys, uint32_t* barmem){
  int i = blockIdx.x * 256 + threadIdx.x;
  if (i < 16320) sigFK[i] = xla_sigmoid(fk[i]);
  else if (i < 16320 + 4096) sigFV[i - 16320] = xla_sigmoid(fv[i - 16320]);

  if (blockIdx.x == 1){
    // zero barrier memory: 1024 leaf words + root word
    for (int k = threadIdx.x; k < 1025; k += 256) barmem[k] = 0u;
  }
  if (blockIdx.x == 0){
    __shared__ int any;
    int t = threadIdx.x;
    if (t == 0) any = 0;
    __syncthreads();
    int bad = 0;
    for (int k = t; k < 1024; k += 256){
      uint32_t w = xw[k];
      if (w != 0u && w != 1u && w != 0x3F800000u) bad = 1;
    }
    if (bad) atomicOr(&any, 1);
    __syncthreads();
    if (t == 0) *flag = any;          // 1 -> u8 layout, 0 -> 4-byte layout

    if (t < 32){
      int b = t >> 2, h = t & 3;
      K2 root{0u, 42u};
      K2 sk = kfold(root, 3u);
      float v[NBIT];
      uint32_t code = 0;
      #pragma unroll
      for (int j = 0; j < NBIT; j++){
        float w = s0w[h*NBIT + j];
        uint32_t p = (uint32_t)((b*4 + h)*NBIT + j);
        float u = bits2u(rbits(sk, p));
        bool bit = u < xla_sigmoid(w);
        code |= (bit ? 1u : 0u) << (NBIT - 1 - j);
        v[j] = bit ? w : -w;
      }
      s0code[t] = (int)code;
      s0s[t]    = neg_lse_neg<NBIT>(v);
    }
    if (t == 0){
      K2 root{0u, 42u};
      K2 rngT = kfold(root, 1u);
      for (int d = 0; d < DEPTH; d++){
        K2 kd = kfold(rngT, (uint32_t)d);
        keys[2*d] = kd.a; keys[2*d+1] = kd.b;
        K2 lk = kfold(rngT, 100u + (uint32_t)d);
        keys[16+2*d] = lk.a; keys[16+2*d+1] = lk.b;
      }
      K2 vk = kfold(rngT, 999u);
      keys[32] = vk.a; keys[33] = vk.b;
      K2 tk = kfold(root, 2u);
      keys[34] = tk.a; keys[35] = tk.b;
    }
  }
}

// ===== Fused phases 1-4; 1024 blocks co-resident (4/CU via launch bounds) =====
__global__ __launch_bounds__(256, 4) void k_fused(
    const void* xraw, const float* xs, const float* fv,
    const float* table, float* out,
    uint8_t* xcode, float* xss, uint8_t* tcode, float* tabs,
    uint8_t* F, uint8_t* zOut, float* P, float* T,
    const int* s0code, const float* s0s, const int* flag,
    const float* sigFK, const float* sigFV, const uint32_t* keys,
    uint32_t* leaves, uint32_t* rootc){

  __shared__ v4i sT4[256];         // 4 KB tcode tile (phases 2/3)
  __shared__ v4i sF4[1024];        // 16 KB F tile (phase 3)
  __shared__ uint8_t sXC[CHUNK];
  __shared__ float carryL[4];
  uint8_t* sT = (uint8_t*)sT4;
  uint8_t* sF = (uint8_t*)sF4;
  const int blk = blockIdx.x;
  const int t = threadIdx.x;

  // ---------- Phase 1: FFN (blocks 0..511) / table (blocks 512..1023) ----------
  if (blk >= 512){
    int idx = (blk - 512) * 256 + t;
    int rem = idx & 16383;
    K2 tk{keys[34], keys[35]};
    float4 w0 = *(const float4*)(table + (size_t)rem*NBIT);
    float4 w1 = *(const float4*)(table + (size_t)rem*NBIT + 4);
    float w[NBIT] = {w0.x,w0.y,w0.z,w0.w,w1.x,w1.y,w1.z,w1.w};
    float v[NBIT];
    uint32_t code = 0;
    #pragma unroll
    for (int j = 0; j < NBIT; j++){
      float u = bits2u(rbits(tk, (uint32_t)idx * 8u + (uint32_t)j));
      bool bit = u < xla_sigmoid(w[j]);
      code |= (bit ? 1u : 0u) << (NBIT - 1 - j);
      v[j] = bit ? w[j] : -w[j];
    }
    cstore_u8(tcode + idx, code);
    cstore_f32(tabs + idx, neg_lse_neg<NBIT>(v));
  } else {
    int r = blk * 256 + t;
    int n = r >> 2;
    int h = r & 3;
    bool u8mode = (*flag != 0);
    const uint8_t* x8   = (const uint8_t*)xraw;
    const uint32_t* x32 = (const uint32_t*)xraw;

    float L0[DD], L1[DD], L2[DD], L3[DD];
    #pragma unroll
    for (int j = 0; j < DD; j++){
      bool qb = u8mode ? (x8[n*DD + j] != 0) : (x32[n*DD + j] != 0u);
      float v = xs[n*DD + j];
      float q = qb ? v : -v;
      float A0 = -xla_logaddexp(-0.0f, q);
      float A1 = -xla_logaddexp(-1.0f, q);
      float B0 = -xla_logaddexp(-0.0f, -q);
      float B1 = -xla_logaddexp(-1.0f, -q);
      L0[j] = xla_logaddexp(A0, B0);
      L1[j] = xla_logaddexp(A1, B0);
      L2[j] = xla_logaddexp(A0, B1);
      L3[j] = xla_logaddexp(A1, B1);
    }

    const float* hb = sigFK + (size_t)h * 255 * 16;
    float cur[16];
    #pragma unroll
    for (int q4 = 0; q4 < 4; q4++)
      *(float4*)(cur + 4*q4) = *(const float4*)(hb + 4*q4);

    uint32_t ix = 0;
    float support = 0.f;

    for (int d = 0; d < 7; d++){
      float cl[16], cr[16];
      {
        const float* cb = hb + (size_t)((2 << d) - 1 + 2*(int)ix) * 16;
        #pragma unroll
        for (int q4 = 0; q4 < 4; q4++){
          *(float4*)(cl + 4*q4) = *(const float4*)(cb + 4*q4);
          *(float4*)(cr + 4*q4) = *(const float4*)(cb + 16 + 4*q4);
        }
      }
      K2 kd{keys[2*d], keys[2*d+1]};
      float lor[DD];
      #pragma unroll
      for (int j = 0; j < DD; j++){
        uint32_t p1 = (uint32_t)r * 16u + 2u*(uint32_t)j;
        float u1 = bits2u(rbits(kd, p1));
        float u2 = bits2u(rbits(kd, p1 + 1u));
        bool b1 = u1 < cur[2*j];
        bool b2 = u2 < cur[2*j + 1];
        float t01 = b1 ? L1[j] : L0[j];
        float t23 = b1 ? L3[j] : L2[j];
        lor[j] = b2 ? t23 : t01;
      }
      float lor_s = neg_lse_neg<DD>(lor);
      K2 lk{keys[16+2*d], keys[16+2*d+1]};
      float ul = bits2u(rbits(lk, (uint32_t)r));
      bool lb = ul < xla_sigmoid(lor_s);
      float ls = lb ? lor_s : -lor_s;
      ix = 2u*ix + (lb ? 1u : 0u);
      support = (d == 0) ? ls : -xla_logaddexp(-support, -ls);
      #pragma unroll
      for (int q = 0; q < 16; q++) cur[q] = lb ? cr[q] : cl[q];
    }

    float fvv[8], sfv[8];
    {
      const float* fb = fv    + (size_t)(h*256 + 2*(int)ix) * VV;
      const float* sb = sigFV + (size_t)(h*256 + 2*(int)ix) * VV;
      *(float4*)(fvv)     = *(const float4*)(fb);
      *(float4*)(fvv + 4) = *(const float4*)(fb + 4);
      *(float4*)(sfv)     = *(const float4*)(sb);
      *(float4*)(sfv + 4) = *(const float4*)(sb + 4);
    }
    {
      const int d = 7;
      K2 kd{keys[2*d], keys[2*d+1]};
      float lor[DD];
      #pragma unroll
      for (int j = 0; j < DD; j++){
        uint32_t p1 = (uint32_t)r * 16u + 2u*(uint32_t)j;
        float u1 = bits2u(rbits(kd, p1));
        float u2 = bits2u(rbits(kd, p1 + 1u));
        bool b1 = u1 < cur[2*j];
        bool b2 = u2 < cur[2*j + 1];
        float t01 = b1 ? L1[j] : L0[j];
        float t23 = b1 ? L3[j] : L2[j];
        lor[j] = b2 ? t23 : t01;
      }
      float lor_s = neg_lse_neg<DD>(lor);
      K2 lk{keys[16+2*d], keys[16+2*d+1]};
      float ul = bits2u(rbits(lk, (uint32_t)r));
      bool lb = ul < xla_sigmoid(lor_s);
      float ls = lb ? lor_s : -lor_s;
      support = -xla_logaddexp(-support, -ls);
      #pragma unroll
      for (int c = 0; c < VV; c++){
        fvv[c] = lb ? fvv[4+c] : fvv[c];
        sfv[c] = lb ? sfv[4+c] : sfv[c];
      }
    }

    K2 vk{keys[32], keys[33]};
    float vs[VV];
    uint32_t code = 0;
    #pragma unroll
    for (int c = 0; c < VV; c++){
      float u = bits2u(rbits(vk, (uint32_t)r*4u + (uint32_t)c));
      bool b = u < sfv[c];
      code |= (b ? 1u : 0u) << (VV - 1 - c);
      float sv = b ? fvv[c] : -fvv[c];
      vs[c] = -xla_logaddexp(-sv, -support);
    }
    cstore_u8(xcode + r, code);
    cstore_f32(xss + r, neg_lse_neg<VV>(vs));
  }
  gbar(leaves, rootc, 1u);

  // ---------- Phase 2: per-chunk all-state maps F (2 vblocks per block) ----------
  for (int v = blk; v < 2048; v += 1024){
    int c  = v & 63;
    int bh = v >> 6;
    int b = bh >> 2, h = bh & 3;
    const int rowbase = (b*64 + h*16) * 256;
    sT4[t] = cload_b128((const v4i*)(tcode + rowbase) + t);
    if (t < CHUNK){
      sXC[t] = (uint8_t)cload_u8(xcode + (b*LL + c*CHUNK + t)*HH + h);
    }
    __syncthreads();
    int cur = t;
    #pragma unroll 8
    for (int k = 0; k < CHUNK; k++){
      cur = sT[(int)sXC[k]*256 + cur];
    }
    cstore_u8(F + (size_t)v*256 + t, (uint32_t)cur);
    __syncthreads();
  }
  gbar(leaves, rootc, 2u);

  // ---------- Phase 3: replay chunk + score scan (4 waves/block, LDS F tile) ----------
  if (blk < 512){
    int bh = blk >> 4;
    int b = bh >> 2, h = bh & 3;
    int w = t >> 6, lane = t & 63;
    int c = (blk & 15)*4 + w;
    const int rowbase = (b*64 + h*16) * 256;
    sT4[t] = cload_b128((const v4i*)(tcode + rowbase) + t);
    // stage F[bh] (16 KB) into LDS — kills the serial global-load chase
    const v4i* Fb4 = (const v4i*)(F + (size_t)bh * 16384);
    #pragma unroll
    for (int i = 0; i < 4; i++) sF4[t + 256*i] = cload_b128(Fb4 + t + 256*i);

    int l = c*CHUNK + lane;
    int r = (b*LL + l)*HH + h;
    int   xcv = (int)cload_u8(xcode + r);
    float xsv = cload_f32(xss + r);
    __syncthreads();

    // redundant carry chase through LDS F tile (~120 cy/step, <=63 steps)
    int z = s0code[bh];
    for (int k = 0; k < c; k++) z = sF[k*256 + z];

    int aReg = 0, zReg = 0;
    for (int k = 0; k < CHUNK; k++){
      int xck = __shfl(xcv, k, 64);
      int a = xck*256 + z;
      z = sT[a];
      if (lane == k){ aReg = a; zReg = z; }
    }

    float p = andf(cload_f32(tabs + rowbase + aReg), xsv);
    #pragma unroll
    for (int off = 1; off < 64; off <<= 1){
      float o = __shfl_up(p, off, 64);
      if (lane >= off) p = andf(o, p);
    }
    int vblk = bh*64 + c;
    cstore_u8(zOut + vblk*CHUNK + lane, (uint32_t)zReg);
    cstore_f32(P + vblk*CHUNK + lane, p);
    if (lane == 63) cstore_f32(T + vblk, p);
  }
  gbar(leaves, rootc, 3u);

  // ---------- Phase 4: score carry + coalesced emit (blocks 0..511) ----------
  if (blk < 512){
    int c = blk & 63;
    int b = blk >> 6;
    int w = t >> 6, lane = t & 63;

    float val = (lane < c) ? cload_f32(T + (b*4 + w)*64 + lane) : AND_IDENT;
    #pragma unroll
    for (int off = 1; off < 64; off <<= 1){
      float o = __shfl_xor(val, off, 64);
      val = andf(val, o);
    }
    float carry = andf(val, s0s[b*4 + w]);
    if (lane == 0) carryL[w] = carry;
    __syncthreads();

    int k = t >> 2, h = t & 3;
    int cblk = (b*4 + h)*64 + c;
    int z = (int)cload_u8(zOut + cblk*CHUNK + k);
    float sc = andf(carryL[h], cload_f32(P + cblk*CHUNK + k));

    size_t base = (size_t)blk*2048 + (size_t)t*8;
    float4 b0, b1;
    b0.x = (float)((z >> 7) & 1); b0.y = (float)((z >> 6) & 1);
    b0.z = (float)((z >> 5) & 1); b0.w = (float)((z >> 4) & 1);
    b1.x = (float)((z >> 3) & 1); b1.y = (float)((z >> 2) & 1);
    b1.z = (float)((z >> 1) & 1); b1.w = (float)( z       & 1);
    float4 s4; s4.x = sc; s4.y = sc; s4.z = sc; s4.w = sc;
    *(float4*)(out + base)     = b0;
    *(float4*)(out + base + 4) = b1;
    *(float4*)(out + 1048576 + base)     = s4;
    *(float4*)(out + 1048576 + base + 4) = s4;
  }
}

extern "C" void kernel_launch(void* const* d_in, const int* in_sizes, int n_in,
                              void* d_out, int out_size, void* d_ws, size_t ws_size,
                              hipStream_t stream) {
  const void*  x      = d_in[0];
  const float* xs     = (const float*)d_in[1];
  const float* fk     = (const float*)d_in[2];
  const float* fv     = (const float*)d_in[3];
  const float* table  = (const float*)d_in[4];
  const float* s0w    = (const float*)d_in[5];
  float* out          = (float*)d_out;

  uint8_t* ws = (uint8_t*)d_ws;
  uint8_t* xcode_ = ws;                              // 131072 B
  uint8_t* tcode_ = ws + 131072;                     // 131072 B
  uint8_t* F_     = ws + 262144;                     // 524288 B
  float*   xss_   = (float*)(ws + 786432);           // 524288 B
  float*   tabs_  = (float*)(ws + 1310720);          // 524288 B
  uint8_t* zOut_  = ws + 1835008;                    // 131072 B
  float*   P_     = (float*)(ws + 1966080);          // 524288 B
  float*   T_     = (float*)(ws + 2490368);          // 8192 B
  int*     s0code_= (int*)  (ws + 2498560);          // 128 B
  float*   s0s_   = (float*)(ws + 2498688);          // 128 B
  int*     flag_  = (int*)  (ws + 2498816);          // 4 B
  float*   sigFK_ = (float*)(ws + 2499072);          // 65280 B
  float*   sigFV_ = (float*)(ws + 2564352);          // 16384 B
  uint32_t* keys_ = (uint32_t*)(ws + 2580736);       // 144 B
  uint32_t* barmem_=(uint32_t*)(ws + 2581504);       // 4100 B: 1024 leaf words + root
  uint32_t* leaves_= barmem_;                        // leaf i at leaves_[i*32] (128B apart)
  uint32_t* rootc_ = barmem_ + 1024;

  k_pre  <<<82, 256, 0, stream>>>((const uint32_t*)x, flag_, s0w, s0code_, s0s_,
                                  fk, fv, sigFK_, sigFV_, keys_, barmem_);
  k_fused<<<GRID, 256, 0, stream>>>(x, xs, fv, table, out,
                                    xcode_, xss_, tcode_, tabs_,
                                    F_, zOut_, P_, T_,
                                    s0code_, s0s_, flag_, sigFK_, sigFV_, keys_,
                                    leaves_, rootc_);
}

// Round 13
// 165.852 us; speedup vs baseline: 1.1090x; 1.0123x over previous
//
#include <hip/hip_runtime.h>
#include <stdint.h>
#include <math.h>

// ===== Problem constants =====
#define BB 8
#define LL 4096
#define HH 4
#define DD 8      // IN_DIM
#define VV 4      // FFN_V
#define DEPTH 8   // FFN_DEPTH
#define NBIT 8
#define NROW 131072   // B*L*H
#define CHUNK 64
#define NCHUNK 64     // L / CHUNK
#define GRID 1024
#define NLEAF 32      // barrier tree leaves (32 blocks/leaf, separate cachelines)

typedef int v4i __attribute__((ext_vector_type(4)));

__device__ __forceinline__ uint32_t rotl32(uint32_t v, int r){ return (v<<r)|(v>>(32-r)); }

__device__ __forceinline__ void tf2x32(uint32_t k0, uint32_t k1, uint32_t x0, uint32_t x1,
                                       uint32_t& o0, uint32_t& o1){
  uint32_t ks2 = k0 ^ k1 ^ 0x1BD11BDAu;
  x0 += k0; x1 += k1;
  x0+=x1; x1=rotl32(x1,13); x1^=x0;
  x0+=x1; x1=rotl32(x1,15); x1^=x0;
  x0+=x1; x1=rotl32(x1,26); x1^=x0;
  x0+=x1; x1=rotl32(x1, 6); x1^=x0;
  x0+=k1; x1+=ks2+1u;
  x0+=x1; x1=rotl32(x1,17); x1^=x0;
  x0+=x1; x1=rotl32(x1,29); x1^=x0;
  x0+=x1; x1=rotl32(x1,16); x1^=x0;
  x0+=x1; x1=rotl32(x1,24); x1^=x0;
  x0+=ks2; x1+=k0+2u;
  x0+=x1; x1=rotl32(x1,13); x1^=x0;
  x0+=x1; x1=rotl32(x1,15); x1^=x0;
  x0+=x1; x1=rotl32(x1,26); x1^=x0;
  x0+=x1; x1=rotl32(x1, 6); x1^=x0;
  x0+=k0; x1+=k1+3u;
  x0+=x1; x1=rotl32(x1,17); x1^=x0;
  x0+=x1; x1=rotl32(x1,29); x1^=x0;
  x0+=x1; x1=rotl32(x1,16); x1^=x0;
  x0+=x1; x1=rotl32(x1,24); x1^=x0;
  x0+=k1; x1+=ks2+4u;
  x0+=x1; x1=rotl32(x1,13); x1^=x0;
  x0+=x1; x1=rotl32(x1,15); x1^=x0;
  x0+=x1; x1=rotl32(x1,26); x1^=x0;
  x0+=x1; x1=rotl32(x1, 6); x1^=x0;
  x0+=ks2; x1+=k0+5u;
  o0 = x0; o1 = x1;
}

struct K2 { uint32_t a, b; };
__device__ __forceinline__ K2 kfold(K2 k, uint32_t d){
  K2 r; tf2x32(k.a, k.b, 0u, d, r.a, r.b); return r;
}

// partitionable threefry (jax >= 0.4.36 default): bits = o0 ^ o1 of tf(key, [0, p])
__device__ __forceinline__ uint32_t rbits(K2 k, uint32_t p){
  uint32_t o0, o1; tf2x32(k.a, k.b, 0u, p, o0, o1); return o0 ^ o1;
}

__device__ __forceinline__ float bits2u(uint32_t b){
  return __uint_as_float((b >> 9) | 0x3f800000u) - 1.0f;
}

// ===== Bit-exact XLA-CPU style math (Cephes/Eigen structure, strict f32, no FMA) =====
__device__ __forceinline__ float xla_expf(float x){
  #pragma clang fp contract(off)
  const float exp_hi = 88.3762626647950f;
  const float exp_lo = -88.3762626647949f;
  const float log2e  = 1.44269504088896341f;
  const float c1 = 0.693359375f;
  const float c2 = -2.12194440e-4f;
  float xc = fmaxf(fminf(x, exp_hi), exp_lo);
  float fx = floorf(xc * log2e + 0.5f);
  float tmp = fx * c1;
  float z1  = fx * c2;
  float r = xc - tmp;
  r = r - z1;
  float z = r * r;
  float y = 1.9875691500E-4f;
  y = y * r + 1.3981999507E-3f;
  y = y * r + 8.3334519073E-3f;
  y = y * r + 4.1665795894E-2f;
  y = y * r + 1.6666665459E-1f;
  y = y * r + 5.0000001201E-1f;
  y = y * z + r;
  y = y + 1.0f;
  int emm0 = (int)fx + 127;
  float scale = __int_as_float(emm0 << 23);
  return fmaxf(y * scale, x);
}

__device__ __forceinline__ float xla_logf(float a){
  #pragma clang fp contract(off)
  float x = fmaxf(a, __uint_as_float(0x00800000u));
  uint32_t bits = __float_as_uint(x);
  int em = (int)(bits >> 23) - 126;
  x = __uint_as_float((bits & 0x007fffffu) | 0x3f000000u);
  float e = (float)em;
  bool mlt = x < 0.707106781186547524f;
  float tmp1 = mlt ? x : 0.0f;
  float xm = x - 1.0f;
  e = e - (mlt ? 1.0f : 0.0f);
  xm = xm + tmp1;
  float z = xm * xm;
  float y = 7.0376836292E-2f;
  y = y * xm + (-1.1514610310E-1f);
  y = y * xm + 1.1676998740E-1f;
  y = y * xm + (-1.2420140846E-1f);
  y = y * xm + 1.4249322787E-1f;
  y = y * xm + (-1.6668057665E-1f);
  y = y * xm + 2.0000714765E-1f;
  y = y * xm + (-2.4999993993E-1f);
  y = y * xm + 3.3333331174E-1f;
  y = y * xm;
  y = y * z;
  y = e * (-2.12194440e-4f) + y;
  y = y - 0.5f * z;
  float res = xm + y;
  res = e * 0.693359375f + res;
  return res;
}

__device__ __forceinline__ float xla_log1pf(float x){
  #pragma clang fp contract(off)
  if (fabsf(x) < 1e-4f){
    return ((-0.5f * x) + 1.0f) * x;
  }
  return xla_logf(1.0f + x);
}

__device__ __forceinline__ float xla_logaddexp(float a, float b){
  #pragma clang fp contract(off)
  float m = fmaxf(a, b);
  float d = a - b;
  return m + xla_log1pf(xla_expf(-fabsf(d)));
}

template<int NV>
__device__ __forceinline__ float neg_lse_neg(const float* v){
  #pragma clang fp contract(off)
  float m = -v[0];
  #pragma unroll
  for (int i = 1; i < NV; i++) m = fmaxf(m, -v[i]);
  float s = 0.f;
  #pragma unroll
  for (int i = 0; i < NV; i++) s = s + xla_expf((-v[i]) - m);
  return -(xla_logf(s) + m);
}

// sigmoid exactly as XLA LogisticExpander: 1/(1+exp(-w))
__device__ __forceinline__ float xla_sigmoid(float w){
  #pragma clang fp contract(off)
  float e = xla_expf(-w);
  return 1.0f / (1.0f + e);
}

// fast soft-AND for analog-only paths: -logaddexp(-a,-b). andf(x, 1e30f)==x.
__device__ __forceinline__ float andf(float a, float b){
  float na = -a, nb = -b;
  float m = fmaxf(na, nb);
  float d = fabsf(na - nb);
  return -(m + log1pf(expf(-d)));
}
#define AND_IDENT 1e30f

// ===== coherence-point access helpers (sc0 sc1 = system scope) =====
__device__ __forceinline__ void cstore_u8(uint8_t* p, uint32_t v){
  asm volatile("global_store_byte %0, %1, off sc0 sc1" :: "v"(p), "v"(v) : "memory");
}
__device__ __forceinline__ void cstore_f32(float* p, float v){
  asm volatile("global_store_dword %0, %1, off sc0 sc1" :: "v"(p), "v"(v) : "memory");
}
__device__ __forceinline__ uint32_t cload_u8(const uint8_t* p){
  uint32_t v;
  asm volatile("global_load_ubyte %0, %1, off sc0 sc1\n\ts_waitcnt vmcnt(0)"
               : "=v"(v) : "v"(p) : "memory");
  return v;
}
__device__ __forceinline__ float cload_f32(const float* p){
  float v;
  asm volatile("global_load_dword %0, %1, off sc0 sc1\n\ts_waitcnt vmcnt(0)"
               : "=v"(v) : "v"(p) : "memory");
  return v;
}
__device__ __forceinline__ uint32_t cload_u32(const uint32_t* p){
  uint32_t v;
  asm volatile("global_load_dword %0, %1, off sc0 sc1\n\ts_waitcnt vmcnt(0)"
               : "=v"(v) : "v"(p) : "memory");
  return v;
}
__device__ __forceinline__ v4i cload_b128(const v4i* p){
  v4i v;
  asm volatile("global_load_dwordx4 %0, %1, off sc0 sc1\n\ts_waitcnt vmcnt(0)"
               : "=v"(v) : "v"(p) : "memory");
  return v;
}

// ===== fence-free tree barrier (round-10 verified) =====
__device__ __forceinline__ void gbar(uint32_t* leaves, uint32_t* root, uint32_t epoch){
  __syncthreads();                    // all waves drain stores (waitcnt before s_barrier)
  if (threadIdx.x == 0){
    uint32_t leaf = blockIdx.x & (NLEAF - 1);
    uint32_t old = atomicAdd(&leaves[leaf * 32], 1u);    // 128B-spaced lines
    if (old + 1u == epoch * (GRID / NLEAF))              // last of this epoch at leaf
      atomicAdd(root, 1u);
    int slp = 1;
    while (cload_u32(root) < epoch * NLEAF){
      for (int i = 0; i < slp; i++) __builtin_amdgcn_s_sleep(15);  // 960 cy
      if (slp < 4) slp <<= 1;
    }
  }
  __syncthreads();
}

// ===== k_pre (82 blocks): sigFK/sigFV + flag + s0 + keys + barrier zero =====
__global__ __launch_bounds__(256) void k_pre(const uint32_t* xw, int* flag,
                      const float* s0w, int* s0code, float* s0s,
                      const float* fk, const float* fv,
                      float* sigFK, float* sigFV, uint32_t* keys, uint32_t* barmem){
  int i = blockIdx.x * 256 + threadIdx.x;
  if (i < 16320) sigFK[i] = xla_sigmoid(fk[i]);
  else if (i < 16320 + 4096) sigFV[i - 16320] = xla_sigmoid(fv[i - 16320]);

  if (blockIdx.x == 1){
    // zero barrier memory: 1024 leaf words + root + tdone
    for (int k = threadIdx.x; k < 1040; k += 256) barmem[k] = 0u;
  }
  if (blockIdx.x == 0){
    __shared__ int any;
    int t = threadIdx.x;
    if (t == 0) any = 0;
    __syncthreads();
    int bad = 0;
    for (int k = t; k < 1024; k += 256){
      uint32_t w = xw[k];
      if (w != 0u && w != 1u && w != 0x3F800000u) bad = 1;
    }
    if (bad) atomicOr(&any, 1);
    __syncthreads();
    if (t == 0) *flag = any;          // 1 -> u8 layout, 0 -> 4-byte layout

    if (t < 32){
      int b = t >> 2, h = t & 3;
      K2 root{0u, 42u};
      K2 sk = kfold(root, 3u);
      float v[NBIT];
      uint32_t code = 0;
      #pragma unroll
      for (int j = 0; j < NBIT; j++){
        float w = s0w[h*NBIT + j];
        uint32_t p = (uint32_t)((b*4 + h)*NBIT + j);
        float u = bits2u(rbits(sk, p));
        bool bit = u < xla_sigmoid(w);
        code |= (bit ? 1u : 0u) << (NBIT - 1 - j);
        v[j] = bit ? w : -w;
      }
      s0code[t] = (int)code;
      s0s[t]    = neg_lse_neg<NBIT>(v);
    }
    if (t == 0){
      K2 root{0u, 42u};
      K2 rngT = kfold(root, 1u);
      for (int d = 0; d < DEPTH; d++){
        K2 kd = kfold(rngT, (uint32_t)d);
        keys[2*d] = kd.a; keys[2*d+1] = kd.b;
        K2 lk = kfold(rngT, 100u + (uint32_t)d);
        keys[16+2*d] = lk.a; keys[16+2*d+1] = lk.b;
      }
      K2 vk = kfold(rngT, 999u);
      keys[32] = vk.a; keys[33] = vk.b;
      K2 tk = kfold(root, 2u);
      keys[34] = tk.a; keys[35] = tk.b;
    }
  }
}

// ===== Fused phases; 1024 blocks co-resident (4/CU via launch bounds) =====
__global__ __launch_bounds__(256, 4) void k_fused(
    const void* xraw, const float* xs, const float* fv,
    const float* table, float* out,
    uint8_t* xcode, float* xss, uint8_t* tcode, float* tabs,
    uint8_t* F, uint8_t* zOut, float* P, float* T,
    const int* s0code, const float* s0s, const int* flag,
    const float* sigFK, const float* sigFV, const uint32_t* keys,
    uint32_t* leaves, uint32_t* rootc, uint32_t* tdone){

  __shared__ v4i sT4[256];         // 4 KB tcode tile (phase 3)
  __shared__ v4i sF4[1024];        // 16 KB: 4 tcode tiles (fused P2) / F tile (P3)
  __shared__ uint8_t sXCf[256];    // own chunk's xcodes, [h*64+k]
  __shared__ float carryL[4];
  uint8_t* sT = (uint8_t*)sT4;
  uint8_t* sF = (uint8_t*)sF4;
  const int blk = blockIdx.x;
  const int t = threadIdx.x;

  // ---------- Phase 1: FFN (blocks 0..511) / table (blocks 512..1023) ----------
  if (blk >= 512){
    int idx = (blk - 512) * 256 + t;
    int rem = idx & 16383;
    K2 tk{keys[34], keys[35]};
    float4 w0 = *(const float4*)(table + (size_t)rem*NBIT);
    float4 w1 = *(const float4*)(table + (size_t)rem*NBIT + 4);
    float w[NBIT] = {w0.x,w0.y,w0.z,w0.w,w1.x,w1.y,w1.z,w1.w};
    float v[NBIT];
    uint32_t code = 0;
    #pragma unroll
    for (int j = 0; j < NBIT; j++){
      float u = bits2u(rbits(tk, (uint32_t)idx * 8u + (uint32_t)j));
      bool bit = u < xla_sigmoid(w[j]);
      code |= (bit ? 1u : 0u) << (NBIT - 1 - j);
      v[j] = bit ? w[j] : -w[j];
    }
    cstore_u8(tcode + idx, code);
    cstore_f32(tabs + idx, neg_lse_neg<NBIT>(v));
    // signal tcode/tabs globally visible (stores drain at the syncthreads)
    __syncthreads();
    if (t == 0) atomicAdd(tdone, 1u);
  } else {
    int r = blk * 256 + t;
    int n = r >> 2;
    int h = r & 3;
    bool u8mode = (*flag != 0);
    const uint8_t* x8   = (const uint8_t*)xraw;
    const uint32_t* x32 = (const uint32_t*)xraw;

    float L0[DD], L1[DD], L2[DD], L3[DD];
    #pragma unroll
    for (int j = 0; j < DD; j++){
      bool qb = u8mode ? (x8[n*DD + j] != 0) : (x32[n*DD + j] != 0u);
      float v = xs[n*DD + j];
      float q = qb ? v : -v;
      float A0 = -xla_logaddexp(-0.0f, q);
      float A1 = -xla_logaddexp(-1.0f, q);
      float B0 = -xla_logaddexp(-0.0f, -q);
      float B1 = -xla_logaddexp(-1.0f, -q);
      L0[j] = xla_logaddexp(A0, B0);
      L1[j] = xla_logaddexp(A1, B0);
      L2[j] = xla_logaddexp(A0, B1);
      L3[j] = xla_logaddexp(A1, B1);
    }

    const float* hb = sigFK + (size_t)h * 255 * 16;
    float cur[16];
    #pragma unroll
    for (int q4 = 0; q4 < 4; q4++)
      *(float4*)(cur + 4*q4) = *(const float4*)(hb + 4*q4);

    uint32_t ix = 0;
    float support = 0.f;
    float fvv[8], sfv[8];

    // software pipeline: depth-d uniforms precomputed, depth-(d+1) hashes
    // issued during depth-d's serial lse8/sigmoid tail (path-independent).
    float u1a[DD], u2a[DD], ulc;
    {
      K2 kd{keys[0], keys[1]};
      #pragma unroll
      for (int j = 0; j < DD; j++){
        uint32_t p1 = (uint32_t)r * 16u + 2u*(uint32_t)j;
        u1a[j] = bits2u(rbits(kd, p1));
        u2a[j] = bits2u(rbits(kd, p1 + 1u));
      }
      K2 lk{keys[16], keys[17]};
      ulc = bits2u(rbits(lk, (uint32_t)r));
    }

    #pragma unroll
    for (int d = 0; d < 8; d++){
      float cl[16], cr[16];
      if (d < 7){
        const float* cb = hb + (size_t)((2 << d) - 1 + 2*(int)ix) * 16;
        #pragma unroll
        for (int q4 = 0; q4 < 4; q4++){
          *(float4*)(cl + 4*q4) = *(const float4*)(cb + 4*q4);
          *(float4*)(cr + 4*q4) = *(const float4*)(cb + 16 + 4*q4);
        }
      } else {
        const float* fb = fv    + (size_t)(h*256 + 2*(int)ix) * VV;
        const float* sb = sigFV + (size_t)(h*256 + 2*(int)ix) * VV;
        *(float4*)(fvv)     = *(const float4*)(fb);
        *(float4*)(fvv + 4) = *(const float4*)(fb + 4);
        *(float4*)(sfv)     = *(const float4*)(sb);
        *(float4*)(sfv + 4) = *(const float4*)(sb + 4);
      }
      // comparisons for depth d (identical values/order to reference)
      float lor[DD];
      #pragma unroll
      for (int j = 0; j < DD; j++){
        bool b1 = u1a[j] < cur[2*j];
        bool b2 = u2a[j] < cur[2*j + 1];
        float t01 = b1 ? L1[j] : L0[j];
        float t23 = b1 ? L3[j] : L2[j];
        lor[j] = b2 ? t23 : t01;
      }
      // next-depth hashes: independent of ix/cur — fills the tail below
      float u1n[DD], u2n[DD], uln = 0.f;
      if (d < 7){
        K2 kd{keys[2*(d+1)], keys[2*(d+1)+1]};
        #pragma unroll
        for (int j = 0; j < DD; j++){
          uint32_t p1 = (uint32_t)r * 16u + 2u*(uint32_t)j;
          u1n[j] = bits2u(rbits(kd, p1));
          u2n[j] = bits2u(rbits(kd, p1 + 1u));
        }
        K2 lk{keys[16+2*(d+1)], keys[16+2*(d+1)+1]};
        uln = bits2u(rbits(lk, (uint32_t)r));
      }
      float lor_s = neg_lse_neg<DD>(lor);
      bool lb = ulc < xla_sigmoid(lor_s);
      float ls = lb ? lor_s : -lor_s;
      ix = 2u*ix + (lb ? 1u : 0u);
      support = (d == 0) ? ls : -xla_logaddexp(-support, -ls);
      if (d < 7){
        #pragma unroll
        for (int q = 0; q < 16; q++) cur[q] = lb ? cr[q] : cl[q];
        #pragma unroll
        for (int j = 0; j < DD; j++){ u1a[j] = u1n[j]; u2a[j] = u2n[j]; }
        ulc = uln;
      } else {
        #pragma unroll
        for (int c = 0; c < VV; c++){
          fvv[c] = lb ? fvv[4+c] : fvv[c];
          sfv[c] = lb ? sfv[4+c] : sfv[c];
        }
      }
    }

    K2 vk{keys[32], keys[33]};
    float vs[VV];
    uint32_t code = 0;
    #pragma unroll
    for (int c = 0; c < VV; c++){
      float u = bits2u(rbits(vk, (uint32_t)r*4u + (uint32_t)c));
      bool b = u < sfv[c];
      code |= (b ? 1u : 0u) << (VV - 1 - c);
      float sv = b ? fvv[c] : -fvv[c];
      vs[c] = -xla_logaddexp(-sv, -support);
    }
    cstore_u8(xcode + r, code);
    cstore_f32(xss + r, neg_lse_neg<VV>(vs));
    sXCf[h*64 + (t >> 2)] = (uint8_t)code;   // h = t&3, k = t>>2 — bijective

    // ---------- Fused phase 2: F-maps for this block's own chunk ----------
    __syncthreads();                          // sXCf visible; xcode/xss drained
    if (t == 0){
      int slp = 1;
      while (cload_u32(tdone) < 512u){        // tcode ready (~6us; we arrive ~65us)
        for (int i = 0; i < slp; i++) __builtin_amdgcn_s_sleep(15);
        if (slp < 4) slp <<= 1;
      }
    }
    __syncthreads();
    int b = blk >> 6, c = blk & 63;
    #pragma unroll
    for (int i = 0; i < 4; i++)
      sF4[i*256 + t] = cload_b128((const v4i*)(tcode + (size_t)(b*64 + i*16)*256) + t);
    __syncthreads();
    // chase all 4 heads as independent chains (4x latency hiding)
    int c0 = t, c1 = t, c2 = t, c3 = t;
    for (int k = 0; k < CHUNK; k++){
      int x0 = sXCf[k],       x1 = sXCf[64 + k];
      int x2 = sXCf[128 + k], x3 = sXCf[192 + k];
      c0 = sF[        x0*256 + c0];
      c1 = sF[ 4096 + x1*256 + c1];
      c2 = sF[ 8192 + x2*256 + c2];
      c3 = sF[12288 + x3*256 + c3];
    }
    cstore_u8(F + (size_t)((b*4 + 0)*64 + c)*256 + t, (uint32_t)c0);
    cstore_u8(F + (size_t)((b*4 + 1)*64 + c)*256 + t, (uint32_t)c1);
    cstore_u8(F + (size_t)((b*4 + 2)*64 + c)*256 + t, (uint32_t)c2);
    cstore_u8(F + (size_t)((b*4 + 3)*64 + c)*256 + t, (uint32_t)c3);
  }
  gbar(leaves, rootc, 1u);

  // ---------- Phase 3: replay chunk + score scan (4 waves/block, LDS F tile) ----------
  if (blk < 512){
    int bh = blk >> 4;
    int b = bh >> 2, h = bh & 3;
    int w = t >> 6, lane = t & 63;
    int c = (blk & 15)*4 + w;
    const int rowbase = (b*64 + h*16) * 256;
    sT4[t] = cload_b128((const v4i*)(tcode + rowbase) + t);
    // stage F[bh] (16 KB) into LDS — kills the serial global-load chase
    const v4i* Fb4 = (const v4i*)(F + (size_t)bh * 16384);
    #pragma unroll
    for (int i = 0; i < 4; i++) sF4[t + 256*i] = cload_b128(Fb4 + t + 256*i);

    int l = c*CHUNK + lane;
    int r = (b*LL + l)*HH + h;
    int   xcv = (int)cload_u8(xcode + r);
    float xsv = cload_f32(xss + r);
    __syncthreads();

    // redundant carry chase through LDS F tile (~120 cy/step, <=63 steps)
    int z = s0code[bh];
    for (int k = 0; k < c; k++) z = sF[k*256 + z];

    int aReg = 0, zReg = 0;
    for (int k = 0; k < CHUNK; k++){
      int xck = __shfl(xcv, k, 64);
      int a = xck*256 + z;
      z = sT[a];
      if (lane == k){ aReg = a; zReg = z; }
    }

    float p = andf(cload_f32(tabs + rowbase + aReg), xsv);
    #pragma unroll
    for (int off = 1; off < 64; off <<= 1){
      float o = __shfl_up(p, off, 64);
      if (lane >= off) p = andf(o, p);
    }
    int vblk = bh*64 + c;
    cstore_u8(zOut + vblk*CHUNK + lane, (uint32_t)zReg);
    cstore_f32(P + vblk*CHUNK + lane, p);
    if (lane == 63) cstore_f32(T + vblk, p);
  }
  gbar(leaves, rootc, 2u);

  // ---------- Phase 4: score carry + coalesced emit (blocks 0..511) ----------
  if (blk < 512){
    int c = blk & 63;
    int b = blk >> 6;
    int w = t >> 6, lane = t & 63;

    float val = (lane < c) ? cload_f32(T + (b*4 + w)*64 + lane) : AND_IDENT;
    #pragma unroll
    for (int off = 1; off < 64; off <<= 1){
      float o = __shfl_xor(val, off, 64);
      val = andf(val, o);
    }
    float carry = andf(val, s0s[b*4 + w]);
    if (lane == 0) carryL[w] = carry;
    __syncthreads();

    int k = t >> 2, h = t & 3;
    int cblk = (b*4 + h)*64 + c;
    int z = (int)cload_u8(zOut + cblk*CHUNK + k);
    float sc = andf(carryL[h], cload_f32(P + cblk*CHUNK + k));

    size_t base = (size_t)blk*2048 + (size_t)t*8;
    float4 b0, b1;
    b0.x = (float)((z >> 7) & 1); b0.y = (float)((z >> 6) & 1);
    b0.z = (float)((z >> 5) & 1); b0.w = (float)((z >> 4) & 1);
    b1.x = (float)((z >> 3) & 1); b1.y = (float)((z >> 2) & 1);
    b1.z = (float)((z >> 1) & 1); b1.w = (float)( z       & 1);
    float4 s4; s4.x = sc; s4.y = sc; s4.z = sc; s4.w = sc;
    *(float4*)(out + base)     = b0;
    *(float4*)(out + base + 4) = b1;
    *(float4*)(out + 1048576 + base)     = s4;
    *(float4*)(out + 1048576 + base + 4) = s4;
  }
}

extern "C" void kernel_launch(void* const* d_in, const int* in_sizes, int n_in,
                              void* d_out, int out_size, void* d_ws, size_t ws_size,
                              hipStream_t stream) {
  const void*  x      = d_in[0];
  const float* xs     = (const float*)d_in[1];
  const float* fk     = (const float*)d_in[2];
  const float* fv     = (const float*)d_in[3];
  const float* table  = (const float*)d_in[4];
  const float* s0w    = (const float*)d_in[5];
  float* out          = (float*)d_out;

  uint8_t* ws = (uint8_t*)d_ws;
  uint8_t* xcode_ = ws;                              // 131072 B
  uint8_t* tcode_ = ws + 131072;                     // 131072 B
  uint8_t* F_     = ws + 262144;                     // 524288 B
  float*   xss_   = (float*)(ws + 786432);           // 524288 B
  float*   tabs_  = (float*)(ws + 1310720);          // 524288 B
  uint8_t* zOut_  = ws + 1835008;                    // 131072 B
  float*   P_     = (float*)(ws + 1966080);          // 524288 B
  float*   T_     = (float*)(ws + 2490368);          // 8192 B
  int*     s0code_= (int*)  (ws + 2498560);          // 128 B
  float*   s0s_   = (float*)(ws + 2498688);          // 128 B
  int*     flag_  = (int*)  (ws + 2498816);          // 4 B
  float*   sigFK_ = (float*)(ws + 2499072);          // 65280 B
  float*   sigFV_ = (float*)(ws + 2564352);          // 16384 B
  uint32_t* keys_ = (uint32_t*)(ws + 2580736);       // 144 B
  uint32_t* barmem_=(uint32_t*)(ws + 2581504);       // 4160 B: 1024 leaves + root + tdone
  uint32_t* leaves_= barmem_;                        // leaf i at leaves_[i*32] (128B apart)
  uint32_t* rootc_ = barmem_ + 1024;
  uint32_t* tdone_ = barmem_ + 1025;

  k_pre  <<<82, 256, 0, stream>>>((const uint32_t*)x, flag_, s0w, s0code_, s0s_,
                                  fk, fv, sigFK_, sigFV_, keys_, barmem_);
  k_fused<<<GRID, 256, 0, stream>>>(x, xs, fv, table, out,
                                    xcode_, xss_, tcode_, tabs_,
                                    F_, zOut_, P_, T_,
                                    s0code_, s0s_, flag_, sigFK_, sigFV_, keys_,
                                    leaves_, rootc_, tdone_);
}